// Round 4
// baseline (508.653 us; speedup 1.0000x reference)
//
#include <hip/hip_runtime.h>
#include <math.h>

// Problem constants
#define Bn 2
#define Vn 6
#define Cn 96
#define Dn 48
#define Hn 48
#define Wn 48
#define THn 96
#define TWn 96
#define EPSf 1e-5f

// padded rz geometry
#define PD 98
#define RZ_VB_PITCH (PD * PD * Cn)          // 921,984 elems
#define RZ_BYTES (12 * RZ_VB_PITCH * 2)     // 22,127,616 B

typedef __attribute__((ext_vector_type(8))) short s8v;   // 8 bf16 (4 VGPRs)
typedef __attribute__((ext_vector_type(4))) float f4v;   // MFMA acc

__device__ __forceinline__ unsigned short f2bf(float f) {
    unsigned int u = __builtin_bit_cast(unsigned int, f);
    u += 0x7FFFu + ((u >> 16) & 1u);          // RNE
    return (unsigned short)(u >> 16);
}
__device__ __forceinline__ float bf2f(unsigned short h) {
    unsigned int u = ((unsigned int)h) << 16;
    return __builtin_bit_cast(float, u);
}

// ---------------------------------------------------------------------------
// K0: weight prep (w1 -> wAt[tap][co][ci] bf16, w2 -> wC[co][ci] bf16),
//     zero BN stat accumulators.
// ---------------------------------------------------------------------------
__global__ __launch_bounds__(256) void k_prep(const float* __restrict__ w1,
                                              const float* __restrict__ w2,
                                              unsigned short* __restrict__ wAt,
                                              unsigned short* __restrict__ wC,
                                              float* __restrict__ stats /*1152*/) {
    int i = blockIdx.x * 256 + threadIdx.x;
    if (i < 82944) {                      // 9*96*96
        int tap = i / 9216;
        int r = i % 9216;
        int co = r / 96, ci = r % 96;
        wAt[i] = f2bf(w1[(co * 96 + ci) * 9 + tap]);
    } else if (i < 92160) {
        int j = i - 82944;
        wC[j] = f2bf(w2[j]);
    } else if (i < 93312) {
        stats[i - 92160] = 0.0f;
    }
}

// ---------------------------------------------------------------------------
// K1: rotated projection -> feat (v,b,y48,x48,c) bf16, c fastest.
// iy == y exactly; bilinear in (x,z), mean over 48 z. 4 channels/thread.
// ---------------------------------------------------------------------------
__global__ __launch_bounds__(256) void k_feat(const float* __restrict__ tokens,
                                              const float* __restrict__ angles,
                                              unsigned short* __restrict__ feat) {
    int idx = blockIdx.x * 256 + threadIdx.x;   // 663,552 total
    int c4 = (idx % 24) * 4;
    int r = idx / 24;
    int x = r % Wn; r /= Wn;
    int y = r % Hn; r /= Hn;
    int b = r & 1;
    int v = r >> 1;

    float th = angles[v];
    float ct = cosf(th), st = sinf(th);
    float X = (x + 0.5f) * (2.0f / 48.0f) - 1.0f;
    float Zc0 = 0.5f * (2.0f / 48.0f) - 1.0f;
    float ix = 24.0f * (ct * X + st * Zc0) + 23.5f;
    float iz = 24.0f * (-st * X + ct * Zc0) + 23.5f;

    const float* tb = tokens + (size_t)b * (Dn * Hn * Wn) * Cn + c4;
    int ybase = y * Wn;

    float a0 = 0.f, a1 = 0.f, a2 = 0.f, a3 = 0.f;
    for (int z = 0; z < Dn; ++z) {
        float x0f = floorf(ix), z0f = floorf(iz);
        float tx = ix - x0f, tz = iz - z0f;
        int x0 = (int)x0f, z0 = (int)z0f;
        float wx[2] = {1.0f - tx, tx};
        float wz[2] = {1.0f - tz, tz};
#pragma unroll
        for (int dz = 0; dz < 2; ++dz) {
            int zc = z0 + dz;
            bool zin = (zc >= 0) && (zc < Dn);
            int zi = min(max(zc, 0), Dn - 1);
            int zoff = zi * (Hn * Wn);
#pragma unroll
            for (int dx = 0; dx < 2; ++dx) {
                int xc = x0 + dx;
                bool xin = (xc >= 0) && (xc < Wn);
                int xi = min(max(xc, 0), Wn - 1);
                float w = wx[dx] * wz[dz] * ((zin && xin) ? 1.0f : 0.0f);
                float4 t = *(const float4*)(tb + (size_t)(zoff + ybase + xi) * Cn);
                a0 += w * t.x; a1 += w * t.y; a2 += w * t.z; a3 += w * t.w;
            }
        }
        ix += st;
        iz += ct;
    }
    const float s = 1.0f / 48.0f;
    ushort4 pk;
    pk.x = f2bf(a0 * s); pk.y = f2bf(a1 * s);
    pk.z = f2bf(a2 * s); pk.w = f2bf(a3 * s);
    *(ushort4*)(&feat[(size_t)(idx / 24) * Cn + c4]) = pk;
}

// ---------------------------------------------------------------------------
// K2: bilinear resize 48x48 -> 96x96 into the ZERO-PADDED rz
// (vb, py=y+1, px=x+1, c) c fastest. 8 ch/thread.
// ---------------------------------------------------------------------------
__global__ __launch_bounds__(256) void k_resize(const unsigned short* __restrict__ feat,
                                                unsigned short* __restrict__ rz) {
    int idx = blockIdx.x * 256 + threadIdx.x;   // 1,327,104 total
    int c8 = (idx % 12) * 8;
    int r = idx / 12;
    int x = r % TWn; r /= TWn;
    int y = r % THn;
    int vb = r / THn;

    float sy = fmaxf(0.5f * (y + 0.5f) - 0.5f, 0.0f);
    int y0 = min((int)sy, Hn - 1);
    int y1 = min(y0 + 1, Hn - 1);
    float ty = sy - (float)y0;
    float sx = fmaxf(0.5f * (x + 0.5f) - 0.5f, 0.0f);
    int x0 = min((int)sx, Wn - 1);
    int x1 = min(x0 + 1, Wn - 1);
    float tx = sx - (float)x0;

    const unsigned short* fb = feat + (size_t)vb * (Hn * Wn * Cn) + c8;
    uint4 r00 = *(const uint4*)(fb + (size_t)(y0 * Wn + x0) * Cn);
    uint4 r01 = *(const uint4*)(fb + (size_t)(y0 * Wn + x1) * Cn);
    uint4 r10 = *(const uint4*)(fb + (size_t)(y1 * Wn + x0) * Cn);
    uint4 r11 = *(const uint4*)(fb + (size_t)(y1 * Wn + x1) * Cn);
    const unsigned int* p00 = (const unsigned int*)&r00;
    const unsigned int* p01 = (const unsigned int*)&r01;
    const unsigned int* p10 = (const unsigned int*)&r10;
    const unsigned int* p11 = (const unsigned int*)&r11;

    float w00 = (1.f - ty) * (1.f - tx), w01 = (1.f - ty) * tx;
    float w10 = ty * (1.f - tx),         w11 = ty * tx;

    unsigned short o[8];
#pragma unroll
    for (int j = 0; j < 8; ++j) {
        int wi = j >> 1, sh = (j & 1) * 16;
        float f00 = bf2f((unsigned short)((p00[wi] >> sh) & 0xFFFFu));
        float f01 = bf2f((unsigned short)((p01[wi] >> sh) & 0xFFFFu));
        float f10 = bf2f((unsigned short)((p10[wi] >> sh) & 0xFFFFu));
        float f11 = bf2f((unsigned short)((p11[wi] >> sh) & 0xFFFFu));
        o[j] = f2bf(w00 * f00 + w01 * f01 + w10 * f10 + w11 * f11);
    }
    uint4 pk;
    pk.x = (unsigned int)o[0] | ((unsigned int)o[1] << 16);
    pk.y = (unsigned int)o[2] | ((unsigned int)o[3] << 16);
    pk.z = (unsigned int)o[4] | ((unsigned int)o[5] << 16);
    pk.w = (unsigned int)o[6] | ((unsigned int)o[7] << 16);
    size_t off = ((size_t)vb * PD + (y + 1)) * PD + (x + 1);
    *(uint4*)(&rz[off * Cn + c8]) = pk;
}

// ---------------------------------------------------------------------------
// K3: conv1 3x3 SAME, implicit GEMM bf16 MFMA 16x16x32.
// Wave = 32 n (2 n-tiles) x 96 co. Per cc-chunk: stage wAt slice (55 KB) to
// LDS; preload all 18 B-frags (unconditional, padded rz); 108 MFMA.
// A-frags via conflict-free contiguous ds_read_b128. Fused BN-stat atomics.
// ---------------------------------------------------------------------------
__global__ __launch_bounds__(256, 2) void k_conv1(const unsigned short* __restrict__ rz,
                                                  const unsigned short* __restrict__ wAt,
                                                  unsigned short* __restrict__ co1,
                                                  float* __restrict__ ssum,
                                                  float* __restrict__ ssq) {
    __shared__ unsigned short Ats[9 * 96 * 32];   // 55,296 B: [tap][co][ci32]

    int blk = blockIdx.x;
    int n0 = blk * 128;                // 9216 % 128 == 0 -> single vb per block
    int vb = n0 / 9216;
    int nl0 = n0 - vb * 9216;

    int t = threadIdx.x;
    int wv = t >> 6;
    int l = t & 63;
    int l15 = l & 15, q = l >> 4;

    int nA = nl0 + wv * 32 + l15;
    int nB = nA + 16;
    int yA = nA / 96, xA = nA - yA * 96;
    int yB = nB / 96, xB = nB - yB * 96;

    // per-lane padded-rz base pointers (+q*8 ci offset); tap offset is const
    const unsigned short* pA = rz + (size_t)vb * RZ_VB_PITCH
                               + (size_t)(yA * PD + xA) * Cn + q * 8;
    const unsigned short* pB = rz + (size_t)vb * RZ_VB_PITCH
                               + (size_t)(yB * PD + xB) * Cn + q * 8;

    f4v acc[2][6];
#pragma unroll
    for (int i = 0; i < 2; ++i)
#pragma unroll
        for (int mt = 0; mt < 6; ++mt) acc[i][mt] = (f4v){0.f, 0.f, 0.f, 0.f};

#pragma unroll
    for (int cc = 0; cc < 96; cc += 32) {
        __syncthreads();
        // stage wAt[:, :, cc..cc+31] -> LDS (3456 x 16B chunks)
        for (int e = t; e < 3456; e += 256) {
            int tap = e / 384;
            int r = e - tap * 384;
            int co = r >> 2;
            int k8 = (r & 3) * 8;
            uint4 v = *(const uint4*)(wAt + tap * 9216 + co * 96 + cc + k8);
            *(uint4*)(&Ats[(size_t)e * 8]) = v;
        }
        __syncthreads();

        // preload all 18 B fragments for this cc chunk (unconditional)
        uint4 braw[2][9];
#pragma unroll
        for (int tap = 0; tap < 9; ++tap) {
            int dy = tap / 3, dx = tap % 3;
            int off = (dy * PD + dx) * Cn + cc;          // compile-time const
            braw[0][tap] = *(const uint4*)(pA + off);
            braw[1][tap] = *(const uint4*)(pB + off);
        }

        // 108 MFMA
#pragma unroll
        for (int tap = 0; tap < 9; ++tap) {
            const unsigned short* ab = &Ats[tap * 3072 + l15 * 32 + q * 8];
#pragma unroll
            for (int mt = 0; mt < 6; ++mt) {
                s8v a = *(const s8v*)(ab + mt * 512);
                acc[0][mt] = __builtin_amdgcn_mfma_f32_16x16x32_bf16(
                    a, __builtin_bit_cast(s8v, braw[0][tap]), acc[0][mt], 0, 0, 0);
                acc[1][mt] = __builtin_amdgcn_mfma_f32_16x16x32_bf16(
                    a, __builtin_bit_cast(s8v, braw[1][tap]), acc[1][mt], 0, 0, 0);
            }
        }
    }

    // epilogue: BN partial stats + bf16 store, layout co1[n][co]
    int vv = vb >> 1;
#pragma unroll
    for (int i = 0; i < 2; ++i) {
        int n = n0 + wv * 32 + i * 16 + l15;
#pragma unroll
        for (int mt = 0; mt < 6; ++mt) {
            float s0 = acc[i][mt][0], s1 = acc[i][mt][1];
            float s2 = acc[i][mt][2], s3 = acc[i][mt][3];
            float q0 = s0 * s0, q1 = s1 * s1, q2 = s2 * s2, q3 = s3 * s3;
#pragma unroll
            for (int off = 1; off < 16; off <<= 1) {
                s0 += __shfl_xor(s0, off); s1 += __shfl_xor(s1, off);
                s2 += __shfl_xor(s2, off); s3 += __shfl_xor(s3, off);
                q0 += __shfl_xor(q0, off); q1 += __shfl_xor(q1, off);
                q2 += __shfl_xor(q2, off); q3 += __shfl_xor(q3, off);
            }
            int co0 = mt * 16 + q * 4;     // D: row(m)=q*4+reg, col(n)=l15
            if (l15 == 0) {
                atomicAdd(&ssum[vv * 96 + co0 + 0], s0);
                atomicAdd(&ssum[vv * 96 + co0 + 1], s1);
                atomicAdd(&ssum[vv * 96 + co0 + 2], s2);
                atomicAdd(&ssum[vv * 96 + co0 + 3], s3);
                atomicAdd(&ssq[vv * 96 + co0 + 0], q0);
                atomicAdd(&ssq[vv * 96 + co0 + 1], q1);
                atomicAdd(&ssq[vv * 96 + co0 + 2], q2);
                atomicAdd(&ssq[vv * 96 + co0 + 3], q3);
            }
            ushort4 pk;
            pk.x = f2bf(acc[i][mt][0]); pk.y = f2bf(acc[i][mt][1]);
            pk.z = f2bf(acc[i][mt][2]); pk.w = f2bf(acc[i][mt][3]);
            *(ushort4*)(&co1[(size_t)n * 96 + co0]) = pk;
        }
    }
}

// ---------------------------------------------------------------------------
// K4: finalize BN -> per (v,c) scale/shift
// ---------------------------------------------------------------------------
__global__ __launch_bounds__(256) void k_musigma(const float* __restrict__ ssum,
                                                 const float* __restrict__ ssq,
                                                 const float* __restrict__ gamma,
                                                 const float* __restrict__ beta,
                                                 float* __restrict__ scale,
                                                 float* __restrict__ shift) {
    int i = blockIdx.x * 256 + threadIdx.x;
    if (i < Vn * Cn) {
        const float invN = 1.0f / (float)(Bn * THn * TWn);
        float mu = ssum[i] * invN;
        float var = ssq[i] * invN - mu * mu;
        float rstd = rsqrtf(fmaxf(var, 0.0f) + EPSf);
        int c = i % Cn;
        float sc = rstd * gamma[c];
        scale[i] = sc;
        shift[i] = beta[c] - mu * sc;
    }
}

// ---------------------------------------------------------------------------
// K5: fused BN + exact GELU (in-register) + conv2 1x1 MFMA + bias +
//     transpose to out (b,v,co,y,x) fp32. wC staged in LDS (pitch 104).
// ---------------------------------------------------------------------------
__global__ __launch_bounds__(256) void k_conv2(const unsigned short* __restrict__ co1,
                                               const unsigned short* __restrict__ wC,
                                               const float* __restrict__ scale,
                                               const float* __restrict__ shift,
                                               const float* __restrict__ b2,
                                               float* __restrict__ out) {
    __shared__ unsigned short Cs[96 * 104];       // 19,968 B, padded pitch
    __shared__ float sscale[96], sshift[96];

    int blk = blockIdx.x;
    int n0 = blk * 128;
    int vb = n0 / 9216;
    int v = vb >> 1, b = vb & 1;

    int t = threadIdx.x;
    int wv = t >> 6;
    int l = t & 63;
    int l15 = l & 15, q = l >> 4;

    if (t < 96) {
        sscale[t] = scale[v * 96 + t];
        sshift[t] = shift[v * 96 + t];
    }
    // stage wC -> LDS [co][ci] with pitch 104 (1152 x 16B chunks)
    for (int e = t; e < 1152; e += 256) {
        int co = e / 12;
        int k8 = (e % 12) * 8;
        uint4 vle = *(const uint4*)(wC + co * 96 + k8);
        *(uint4*)(&Cs[co * 104 + k8]) = vle;
    }
    __syncthreads();

    f4v acc[2][6];
#pragma unroll
    for (int i = 0; i < 2; ++i)
#pragma unroll
        for (int mt = 0; mt < 6; ++mt) acc[i][mt] = (f4v){0.f, 0.f, 0.f, 0.f};

    int nA = n0 + wv * 32 + l15;

    // preload all 6 activation frags, then GELU in-register
    uint4 raw[2][3];
#pragma unroll
    for (int ks = 0; ks < 3; ++ks) {
        int ci0 = ks * 32 + q * 8;
        raw[0][ks] = *(const uint4*)(co1 + (size_t)nA * 96 + ci0);
        raw[1][ks] = *(const uint4*)(co1 + (size_t)(nA + 16) * 96 + ci0);
    }
    s8v bf[2][3];
#pragma unroll
    for (int ks = 0; ks < 3; ++ks) {
        int ci0 = ks * 32 + q * 8;
#pragma unroll
        for (int i = 0; i < 2; ++i) {
            const unsigned int* pw = (const unsigned int*)&raw[i][ks];
            unsigned short o[8];
#pragma unroll
            for (int j = 0; j < 8; ++j) {
                unsigned short h = (unsigned short)((pw[j >> 1] >> ((j & 1) * 16)) & 0xFFFFu);
                float yv = bf2f(h) * sscale[ci0 + j] + sshift[ci0 + j];
                float g = 0.5f * yv * (1.0f + erff(yv * 0.70710678118654752f));
                o[j] = f2bf(g);
            }
            uint4 pk;
            pk.x = (unsigned int)o[0] | ((unsigned int)o[1] << 16);
            pk.y = (unsigned int)o[2] | ((unsigned int)o[3] << 16);
            pk.z = (unsigned int)o[4] | ((unsigned int)o[5] << 16);
            pk.w = (unsigned int)o[6] | ((unsigned int)o[7] << 16);
            bf[i][ks] = __builtin_bit_cast(s8v, pk);
        }
    }

#pragma unroll
    for (int ks = 0; ks < 3; ++ks) {
        const unsigned short* ab = &Cs[l15 * 104 + ks * 32 + q * 8];
#pragma unroll
        for (int mt = 0; mt < 6; ++mt) {
            s8v a = *(const s8v*)(ab + mt * 16 * 104);
            acc[0][mt] = __builtin_amdgcn_mfma_f32_16x16x32_bf16(a, bf[0][ks], acc[0][mt], 0, 0, 0);
            acc[1][mt] = __builtin_amdgcn_mfma_f32_16x16x32_bf16(a, bf[1][ks], acc[1][mt], 0, 0, 0);
        }
    }

    int nl0 = n0 - vb * 9216;
    size_t obase = ((size_t)(b * Vn + v) * Cn) * 9216;
#pragma unroll
    for (int i = 0; i < 2; ++i) {
        int nl = nl0 + wv * 32 + i * 16 + l15;
#pragma unroll
        for (int mt = 0; mt < 6; ++mt) {
            int co0 = mt * 16 + q * 4;
#pragma unroll
            for (int reg = 0; reg < 4; ++reg) {
                int co = co0 + reg;
                out[obase + (size_t)co * 9216 + nl] = acc[i][mt][reg] + b2[co];
            }
        }
    }
}

// ---------------------------------------------------------------------------
extern "C" void kernel_launch(void* const* d_in, const int* in_sizes, int n_in,
                              void* d_out, int out_size, void* d_ws, size_t ws_size,
                              hipStream_t stream) {
    const float* tokens = (const float*)d_in[0];
    const float* angles = (const float*)d_in[1];
    const float* w1     = (const float*)d_in[2];
    const float* gamma  = (const float*)d_in[3];
    const float* beta   = (const float*)d_in[4];
    const float* w2     = (const float*)d_in[5];
    const float* b2     = (const float*)d_in[6];
    float* out = (float*)d_out;

    // workspace layout (bytes)
    char* ws = (char*)d_ws;
    unsigned short* feat = (unsigned short*)(ws);                 //  5,308,416
    unsigned short* rz   = (unsigned short*)(ws + 5308416);       // 22,127,616 (padded)
    unsigned short* co1  = (unsigned short*)(ws + 27436032);      // 21,233,664
    unsigned short* wAt  = (unsigned short*)(ws + 48669696);      //    165,888
    unsigned short* wC   = (unsigned short*)(ws + 48835584);      //     18,432
    float* ssum  = (float*)(ws + 48854016);                       //      2,304
    float* ssq   = ssum + 576;
    float* scale = (float*)(ws + 48858624);
    float* shift = scale + 576;

    hipMemsetAsync(rz, 0, RZ_BYTES, stream);   // zero halo for padded rz

    k_prep<<<365, 256, 0, stream>>>(w1, w2, wAt, wC, ssum);
    k_feat<<<2592, 256, 0, stream>>>(tokens, angles, feat);
    k_resize<<<5184, 256, 0, stream>>>(feat, rz);
    k_conv1<<<864, 256, 0, stream>>>(rz, wAt, co1, ssum, ssq);
    k_musigma<<<3, 256, 0, stream>>>(ssum, ssq, gamma, beta, scale, shift);
    k_conv2<<<864, 256, 0, stream>>>(co1, wC, scale, shift, b2, out);
}

// Round 5
// 334.120 us; speedup vs baseline: 1.5224x; 1.5224x over previous
//
#include <hip/hip_runtime.h>
#include <math.h>

// Problem constants
#define Bn 2
#define Vn 6
#define Cn 96
#define Dn 48
#define Hn 48
#define Wn 48
#define THn 96
#define TWn 96
#define EPSf 1e-5f

// packetized geometry: 16B packets of 8 consecutive ci
#define PD 98
#define NCI8 12
// rz:  (((vb*PD+py)*NCI8 + ci8)*PD + px)*8 + e     (bf16, zero-padded halo)
// co1: (((vb*NCI8+co8)*9216 + n)*8 + e             (bf16)
// wAtP:(((tap*NCI8+ci8)*96 + co)*8 + e             (bf16)
// wCP: ((ci8*96 + co)*8 + e                        (bf16)
#define RZ_VB (PD * NCI8 * PD * 8)
#define RZ_BYTES (12 * RZ_VB * 2)                   // 22,127,616

typedef __attribute__((ext_vector_type(8))) short s8v;   // 8 bf16
typedef __attribute__((ext_vector_type(4))) float f4v;   // MFMA acc

__device__ __forceinline__ unsigned short f2bf(float f) {
    unsigned int u = __builtin_bit_cast(unsigned int, f);
    u += 0x7FFFu + ((u >> 16) & 1u);          // RNE
    return (unsigned short)(u >> 16);
}
__device__ __forceinline__ float bf2f(unsigned short h) {
    unsigned int u = ((unsigned int)h) << 16;
    return __builtin_bit_cast(float, u);
}
__device__ __forceinline__ void unpack8(uint4 r, float* f) {
    unsigned int w[4] = {r.x, r.y, r.z, r.w};
#pragma unroll
    for (int j = 0; j < 8; ++j)
        f[j] = bf2f((unsigned short)((w[j >> 1] >> ((j & 1) * 16)) & 0xFFFFu));
}
__device__ __forceinline__ uint4 pack8(const unsigned short* o) {
    uint4 pk;
    pk.x = (unsigned int)o[0] | ((unsigned int)o[1] << 16);
    pk.y = (unsigned int)o[2] | ((unsigned int)o[3] << 16);
    pk.z = (unsigned int)o[4] | ((unsigned int)o[5] << 16);
    pk.w = (unsigned int)o[6] | ((unsigned int)o[7] << 16);
    return pk;
}

// ---------------------------------------------------------------------------
// K0: weight prep into packet layouts.
// ---------------------------------------------------------------------------
__global__ __launch_bounds__(256) void k_prep(const float* __restrict__ w1,
                                              const float* __restrict__ w2,
                                              unsigned short* __restrict__ wAtP,
                                              unsigned short* __restrict__ wCP) {
    int i = blockIdx.x * 256 + threadIdx.x;
    if (i < 82944) {                       // 9*12*96*8
        int e = i & 7;
        int u = i >> 3;
        int co = u % 96;
        int u2 = u / 96;                   // tap*12 + ci8
        int ci8 = u2 % NCI8;
        int tap = u2 / NCI8;
        wAtP[i] = f2bf(w1[(co * 96 + ci8 * 8 + e) * 9 + tap]);
    } else if (i < 92160) {
        int j = i - 82944;
        int e = j & 7;
        int u = j >> 3;
        int co = u % 96;
        int ci8 = u / 96;
        wCP[j] = f2bf(w2[co * 96 + ci8 * 8 + e]);
    }
}

// ---------------------------------------------------------------------------
// K0b: tokens fp32 -> bf16 (same layout), coalesced.
// ---------------------------------------------------------------------------
__global__ __launch_bounds__(256) void k_tok(const float* __restrict__ tokens,
                                             unsigned short* __restrict__ tokB) {
    int idx = blockIdx.x * 256 + threadIdx.x;      // 2,654,208 threads
    size_t base = (size_t)idx * 8;
    float4 f0 = *(const float4*)(tokens + base);
    float4 f1 = *(const float4*)(tokens + base + 4);
    unsigned short o[8] = {f2bf(f0.x), f2bf(f0.y), f2bf(f0.z), f2bf(f0.w),
                           f2bf(f1.x), f2bf(f1.y), f2bf(f1.z), f2bf(f1.w)};
    *(uint4*)(&tokB[base]) = pack8(o);
}

// ---------------------------------------------------------------------------
// K1: rotated projection -> featP[vb][y48][ci8][x48][8] bf16.
// iy == y exactly; bilinear in (x,z), mean over 48 z. 8 channels/thread.
// ---------------------------------------------------------------------------
__global__ __launch_bounds__(256) void k_feat(const unsigned short* __restrict__ tokB,
                                              const float* __restrict__ angles,
                                              unsigned short* __restrict__ featP) {
    int idx = blockIdx.x * 256 + threadIdx.x;   // 331,776 total
    int c8i = idx % NCI8;
    int r = idx / NCI8;
    int x = r % Wn; r /= Wn;
    int y = r % Hn; r /= Hn;
    int b = r & 1;
    int v = r >> 1;
    int vb = v * 2 + b;

    float th = angles[v];
    float ct = cosf(th), st = sinf(th);
    float X = (x + 0.5f) * (2.0f / 48.0f) - 1.0f;
    float Zc0 = 0.5f * (2.0f / 48.0f) - 1.0f;
    float ix = 24.0f * (ct * X + st * Zc0) + 23.5f;
    float iz = 24.0f * (-st * X + ct * Zc0) + 23.5f;

    const unsigned short* tb = tokB + (size_t)b * (Dn * Hn * Wn) * Cn + c8i * 8;
    int ybase = y * Wn;

    float af[8] = {0.f, 0.f, 0.f, 0.f, 0.f, 0.f, 0.f, 0.f};
    for (int z = 0; z < Dn; ++z) {
        float x0f = floorf(ix), z0f = floorf(iz);
        float tx = ix - x0f, tz = iz - z0f;
        int x0 = (int)x0f, z0 = (int)z0f;
        float wx[2] = {1.0f - tx, tx};
        float wz[2] = {1.0f - tz, tz};
#pragma unroll
        for (int dz = 0; dz < 2; ++dz) {
            int zc = z0 + dz;
            bool zin = (zc >= 0) && (zc < Dn);
            int zi = min(max(zc, 0), Dn - 1);
            int zoff = zi * (Hn * Wn);
#pragma unroll
            for (int dx = 0; dx < 2; ++dx) {
                int xc = x0 + dx;
                bool xin = (xc >= 0) && (xc < Wn);
                int xi = min(max(xc, 0), Wn - 1);
                float w = wx[dx] * wz[dz] * ((zin && xin) ? 1.0f : 0.0f);
                uint4 raw = *(const uint4*)(tb + (size_t)(zoff + ybase + xi) * Cn);
                float f[8];
                unpack8(raw, f);
#pragma unroll
                for (int j = 0; j < 8; ++j) af[j] += w * f[j];
            }
        }
        ix += st;
        iz += ct;
    }
    const float s = 1.0f / 48.0f;
    unsigned short o[8];
#pragma unroll
    for (int j = 0; j < 8; ++j) o[j] = f2bf(af[j] * s);
    size_t off = (((size_t)vb * Hn + y) * NCI8 + c8i) * Wn + x;
    *(uint4*)(&featP[off * 8]) = pack8(o);
}

// ---------------------------------------------------------------------------
// K2: bilinear resize 48->96 into zero-padded packetized rz. x-fastest lanes:
// coalesced packet reads (2-lane broadcast) and contiguous packet writes.
// ---------------------------------------------------------------------------
__global__ __launch_bounds__(256) void k_resize(const unsigned short* __restrict__ featP,
                                                unsigned short* __restrict__ rz) {
    int idx = blockIdx.x * 256 + threadIdx.x;   // 1,327,104 total
    int x = idx % TWn;
    int r = idx / TWn;
    int c8i = r % NCI8; r /= NCI8;
    int y = r % THn;
    int vb = r / THn;

    float sy = fmaxf(0.5f * (y + 0.5f) - 0.5f, 0.0f);
    int y0 = min((int)sy, Hn - 1);
    int y1 = min(y0 + 1, Hn - 1);
    float ty = sy - (float)y0;
    float sx = fmaxf(0.5f * (x + 0.5f) - 0.5f, 0.0f);
    int x0 = min((int)sx, Wn - 1);
    int x1 = min(x0 + 1, Wn - 1);
    float tx = sx - (float)x0;

    const unsigned short* fb = featP + ((size_t)vb * Hn * NCI8 + c8i) * Wn * 8;
    // row bases for y0/y1 at this c8 plane
    const unsigned short* r0 = fb + (size_t)y0 * (NCI8 * Wn * 8);
    const unsigned short* r1 = fb + (size_t)y1 * (NCI8 * Wn * 8);
    uint4 q00 = *(const uint4*)(r0 + (size_t)x0 * 8);
    uint4 q01 = *(const uint4*)(r0 + (size_t)x1 * 8);
    uint4 q10 = *(const uint4*)(r1 + (size_t)x0 * 8);
    uint4 q11 = *(const uint4*)(r1 + (size_t)x1 * 8);
    float f00[8], f01[8], f10[8], f11[8];
    unpack8(q00, f00); unpack8(q01, f01); unpack8(q10, f10); unpack8(q11, f11);

    float w00 = (1.f - ty) * (1.f - tx), w01 = (1.f - ty) * tx;
    float w10 = ty * (1.f - tx),         w11 = ty * tx;

    unsigned short o[8];
#pragma unroll
    for (int j = 0; j < 8; ++j)
        o[j] = f2bf(w00 * f00[j] + w01 * f01[j] + w10 * f10[j] + w11 * f11[j]);

    size_t off = (((size_t)vb * PD + (y + 1)) * NCI8 + c8i) * PD + (x + 1);
    *(uint4*)(&rz[off * 8]) = pack8(o);
}

// ---------------------------------------------------------------------------
// K3: conv1 3x3 SAME, implicit GEMM bf16 MFMA 16x16x32. ZERO LDS.
// Wave = 64 n (4 tiles) x 96 co. All loads are 16B packets where the 16 lanes
// of a quad-group are contiguous (256B segments). 648 MFMA/wave, no barriers.
// ---------------------------------------------------------------------------
__global__ __launch_bounds__(256) void k_conv1(const unsigned short* __restrict__ rz,
                                               const unsigned short* __restrict__ wAtP,
                                               unsigned short* __restrict__ co1) {
    int blk = blockIdx.x;
    int n0 = blk * 256;                // 9216 % 256 == 0 -> single vb
    int vb = n0 / 9216;
    int nl0 = n0 - vb * 9216;

    int t = threadIdx.x;
    int wv = t >> 6;
    int l = t & 63;
    int l15 = l & 15, q = l >> 4;

    int nt0 = nl0 + wv * 64;
    int nl[4];
    const unsigned short* pB[4];
#pragma unroll
    for (int i = 0; i < 4; ++i) {
        nl[i] = nt0 + i * 16 + l15;
        int y = nl[i] / 96, x = nl[i] - y * 96;
        // base at (py=y, ci8=0, px=x); taps add (dy*NCI8*PD + ci8*PD + dx)*8
        pB[i] = rz + ((((size_t)vb * PD + y) * NCI8) * PD + x) * 8;
    }

    f4v acc[4][6];
#pragma unroll
    for (int i = 0; i < 4; ++i)
#pragma unroll
        for (int mt = 0; mt < 6; ++mt) acc[i][mt] = (f4v){0.f, 0.f, 0.f, 0.f};

#pragma unroll
    for (int ks = 0; ks < 3; ++ks) {
        int ci8 = ks * 4 + q;
        const unsigned short* pb0 = pB[0] + (size_t)ci8 * (PD * 8);
        const unsigned short* pb1 = pB[1] + (size_t)ci8 * (PD * 8);
        const unsigned short* pb2 = pB[2] + (size_t)ci8 * (PD * 8);
        const unsigned short* pb3 = pB[3] + (size_t)ci8 * (PD * 8);
        const unsigned short* pa = wAtP + ((size_t)ci8 * 96 + l15) * 8;
#pragma unroll
        for (int tap = 0; tap < 9; ++tap) {
            int dy = tap / 3, dx = tap % 3;
            size_t toff = ((size_t)dy * (NCI8 * PD) + dx) * 8;   // const
            s8v b0 = *(const s8v*)(pb0 + toff);
            s8v b1 = *(const s8v*)(pb1 + toff);
            s8v b2 = *(const s8v*)(pb2 + toff);
            s8v b3 = *(const s8v*)(pb3 + toff);
            const unsigned short* ap = pa + (size_t)tap * (NCI8 * 96 * 8);
#pragma unroll
            for (int mt = 0; mt < 6; ++mt) {
                s8v a = *(const s8v*)(ap + (size_t)mt * (16 * 8));
                acc[0][mt] = __builtin_amdgcn_mfma_f32_16x16x32_bf16(a, b0, acc[0][mt], 0, 0, 0);
                acc[1][mt] = __builtin_amdgcn_mfma_f32_16x16x32_bf16(a, b1, acc[1][mt], 0, 0, 0);
                acc[2][mt] = __builtin_amdgcn_mfma_f32_16x16x32_bf16(a, b2, acc[2][mt], 0, 0, 0);
                acc[3][mt] = __builtin_amdgcn_mfma_f32_16x16x32_bf16(a, b3, acc[3][mt], 0, 0, 0);
            }
        }
    }

    // store to packetized co1 (no stats here)
#pragma unroll
    for (int i = 0; i < 4; ++i) {
#pragma unroll
        for (int mt = 0; mt < 6; ++mt) {
            int co0 = mt * 16 + q * 4;         // D: row(m)=q*4+reg, col(n)=l15
            ushort4 pk;
            pk.x = f2bf(acc[i][mt][0]); pk.y = f2bf(acc[i][mt][1]);
            pk.z = f2bf(acc[i][mt][2]); pk.w = f2bf(acc[i][mt][3]);
            size_t off = (((size_t)vb * NCI8 + (co0 >> 3)) * 9216 + nl[i]) * 8 + (co0 & 7);
            *(ushort4*)(&co1[off]) = pk;
        }
    }
}

// ---------------------------------------------------------------------------
// K4: BN stats from co1 (coalesced packet reads) -> per (v,c) scale/shift.
// One block per (v, co8).
// ---------------------------------------------------------------------------
__global__ __launch_bounds__(256) void k_stats(const unsigned short* __restrict__ co1,
                                               const float* __restrict__ gamma,
                                               const float* __restrict__ beta,
                                               float* __restrict__ scale,
                                               float* __restrict__ shift) {
    int v = blockIdx.x / NCI8;
    int c8 = blockIdx.x % NCI8;
    int t = threadIdx.x;

    float s[8] = {0,0,0,0,0,0,0,0}, ss[8] = {0,0,0,0,0,0,0,0};
#pragma unroll
    for (int bb = 0; bb < 2; ++bb) {
        const unsigned short* p = co1 + (((size_t)(v * 2 + bb) * NCI8 + c8) * 9216) * 8;
        for (int n = t; n < 9216; n += 256) {
            uint4 raw = *(const uint4*)(p + (size_t)n * 8);
            float f[8];
            unpack8(raw, f);
#pragma unroll
            for (int j = 0; j < 8; ++j) { s[j] += f[j]; ss[j] += f[j] * f[j]; }
        }
    }
#pragma unroll
    for (int off = 1; off < 64; off <<= 1) {
#pragma unroll
        for (int j = 0; j < 8; ++j) {
            s[j]  += __shfl_xor(s[j],  off);
            ss[j] += __shfl_xor(ss[j], off);
        }
    }
    __shared__ float rs[4][8], rss[4][8];
    int wv = t >> 6;
    if ((t & 63) == 0) {
#pragma unroll
        for (int j = 0; j < 8; ++j) { rs[wv][j] = s[j]; rss[wv][j] = ss[j]; }
    }
    __syncthreads();
    if (t < 8) {
        int j = t;
        float S = rs[0][j] + rs[1][j] + rs[2][j] + rs[3][j];
        float SS = rss[0][j] + rss[1][j] + rss[2][j] + rss[3][j];
        const float invN = 1.0f / (float)(Bn * THn * TWn);
        float mu = S * invN;
        float var = SS * invN - mu * mu;
        float rstd = rsqrtf(fmaxf(var, 0.0f) + EPSf);
        int c = c8 * 8 + j;
        float sc = rstd * gamma[c];
        scale[v * 96 + c] = sc;
        shift[v * 96 + c] = beta[c] - mu * sc;
    }
}

// ---------------------------------------------------------------------------
// K5: fused BN + exact GELU (in-register) + conv2 1x1 MFMA + bias +
//     transpose to out (b,v,co,y,x) fp32. ZERO weight-LDS gathers: packets.
// ---------------------------------------------------------------------------
__global__ __launch_bounds__(256) void k_conv2(const unsigned short* __restrict__ co1,
                                               const unsigned short* __restrict__ wCP,
                                               const float* __restrict__ scale,
                                               const float* __restrict__ shift,
                                               const float* __restrict__ b2,
                                               float* __restrict__ out) {
    __shared__ float ssc[96], ssh[96], sbias[96];

    int blk = blockIdx.x;
    int n0 = blk * 256;
    int vb = n0 / 9216;
    int nl0 = n0 - vb * 9216;
    int v = vb >> 1, b = vb & 1;

    int t = threadIdx.x;
    int wv = t >> 6;
    int l = t & 63;
    int l15 = l & 15, q = l >> 4;

    if (t < 96) {
        ssc[t] = scale[v * 96 + t];
        ssh[t] = shift[v * 96 + t];
        sbias[t] = b2[t];
    }
    __syncthreads();

    int nt0 = nl0 + wv * 64;

    f4v acc[4][6];
#pragma unroll
    for (int i = 0; i < 4; ++i)
#pragma unroll
        for (int mt = 0; mt < 6; ++mt) acc[i][mt] = (f4v){0.f, 0.f, 0.f, 0.f};

#pragma unroll
    for (int ks = 0; ks < 3; ++ks) {
        int ci8 = ks * 4 + q;
        int ci0 = ci8 * 8;
        float sc[8], sh[8];
#pragma unroll
        for (int j = 0; j < 8; ++j) { sc[j] = ssc[ci0 + j]; sh[j] = ssh[ci0 + j]; }

        const unsigned short* pb = co1 + (((size_t)vb * NCI8 + ci8) * 9216) * 8;
        s8v bfr[4];
#pragma unroll
        for (int i = 0; i < 4; ++i) {
            int n = nt0 + i * 16 + l15;
            uint4 raw = *(const uint4*)(pb + (size_t)n * 8);
            float f[8];
            unpack8(raw, f);
            unsigned short o[8];
#pragma unroll
            for (int j = 0; j < 8; ++j) {
                float yv = f[j] * sc[j] + sh[j];
                float g = 0.5f * yv * (1.0f + erff(yv * 0.70710678118654752f));
                o[j] = f2bf(g);
            }
            bfr[i] = __builtin_bit_cast(s8v, pack8(o));
        }
        const unsigned short* pa = wCP + ((size_t)ci8 * 96 + l15) * 8;
#pragma unroll
        for (int mt = 0; mt < 6; ++mt) {
            s8v a = *(const s8v*)(pa + (size_t)mt * (16 * 8));
#pragma unroll
            for (int i = 0; i < 4; ++i)
                acc[i][mt] = __builtin_amdgcn_mfma_f32_16x16x32_bf16(a, bfr[i], acc[i][mt], 0, 0, 0);
        }
    }

    size_t obase = ((size_t)(b * Vn + v) * Cn) * 9216;
#pragma unroll
    for (int i = 0; i < 4; ++i) {
        int nl = nt0 + i * 16 + l15;
#pragma unroll
        for (int mt = 0; mt < 6; ++mt) {
            int co0 = mt * 16 + q * 4;
#pragma unroll
            for (int reg = 0; reg < 4; ++reg) {
                int co = co0 + reg;
                out[obase + (size_t)co * 9216 + nl] = acc[i][mt][reg] + sbias[co];
            }
        }
    }
}

// ---------------------------------------------------------------------------
extern "C" void kernel_launch(void* const* d_in, const int* in_sizes, int n_in,
                              void* d_out, int out_size, void* d_ws, size_t ws_size,
                              hipStream_t stream) {
    const float* tokens = (const float*)d_in[0];
    const float* angles = (const float*)d_in[1];
    const float* w1     = (const float*)d_in[2];
    const float* gamma  = (const float*)d_in[3];
    const float* beta   = (const float*)d_in[4];
    const float* w2     = (const float*)d_in[5];
    const float* b2     = (const float*)d_in[6];
    float* out = (float*)d_out;

    // workspace layout (bytes) — tokB aliases [rz .. co1) (dead after k_feat)
    char* ws = (char*)d_ws;
    unsigned short* featP = (unsigned short*)(ws);                //  5,308,416
    unsigned short* tokB  = (unsigned short*)(ws + 5308416);      // 42,467,328 (alias)
    unsigned short* rz    = (unsigned short*)(ws + 5308416);      // 22,127,616
    unsigned short* co1   = (unsigned short*)(ws + 27436032);     // 21,233,664
    unsigned short* wAtP  = (unsigned short*)(ws + 48669696);     //    165,888
    unsigned short* wCP   = (unsigned short*)(ws + 48835584);     //     18,432
    float* scale = (float*)(ws + 48854016);                       //      2,304
    float* shift = (float*)(ws + 48856320);                       //      2,304

    k_prep<<<360, 256, 0, stream>>>(w1, w2, wAtP, wCP);
    k_tok<<<10368, 256, 0, stream>>>(tokens, tokB);
    k_feat<<<1296, 256, 0, stream>>>(tokB, angles, featP);
    hipMemsetAsync(rz, 0, RZ_BYTES, stream);      // tokB dead; zero halo
    k_resize<<<5184, 256, 0, stream>>>(featP, rz);
    k_conv1<<<432, 256, 0, stream>>>(rz, wAtP, co1);
    k_stats<<<72, 256, 0, stream>>>(co1, gamma, beta, scale, shift);
    k_conv2<<<432, 256, 0, stream>>>(co1, wCP, scale, shift, b2, out);
}